// Round 2
// baseline (329.318 us; speedup 1.0000x reference)
//
#include <hip/hip_runtime.h>

// ANet fused forward: x[B,64] -> fc1/relu -> fc2/tanh -> opt layer -> capped-simplex projection.
// One thread per row; everything in registers; weights via uniform (scalar) loads.

constexpr int SDIM  = 64;
constexpr int HID   = 30;
constexpr int ADIM  = 32;
constexpr int BATCH = 524288;
constexpr float BUDGET = 90.0f;
constexpr int NBIS = 24;   // bracket ~10.1 wide -> lam err ~3e-7 << 5.66e-2 threshold

static __device__ __forceinline__ float fast_exp2(float a) {
#if __has_builtin(__builtin_amdgcn_exp2f)
    return __builtin_amdgcn_exp2f(a);   // v_exp_f32
#else
    return exp2f(a);
#endif
}

__global__ __launch_bounds__(256) void anet_fused(
    const float* __restrict__ x,
    const float* __restrict__ W1, const float* __restrict__ b1,
    const float* __restrict__ W2, const float* __restrict__ b2,
    const float* __restrict__ Wopt, const float* __restrict__ bopt,
    const float* __restrict__ u,
    float* __restrict__ out)
{
    const long long row = (long long)blockIdx.x * blockDim.x + threadIdx.x;

    // ---- load x row (16 x float4, dense per-thread-row pattern) ----
    const float4* __restrict__ xp = reinterpret_cast<const float4*>(x + row * SDIM);
    float xr[SDIM];
#pragma unroll
    for (int i = 0; i < SDIM / 4; ++i) {
        const float4 v = xp[i];
        xr[4*i+0] = v.x; xr[4*i+1] = v.y; xr[4*i+2] = v.z; xr[4*i+3] = v.w;
    }

    // ---- fc1 + relu: h[j] = relu(sum_k x[k]*W1[j,k] + b1[j]) ----
    float h[HID];
#pragma unroll
    for (int j = 0; j < HID; ++j) {
        float acc = b1[j];
#pragma unroll
        for (int k = 0; k < SDIM; ++k)
            acc = fmaf(xr[k], W1[j * SDIM + k], acc);
        h[j] = fmaxf(acc, 0.0f);
    }

    // ---- fc2 + tanh: t[i] = tanh(sum_j h[j]*W2[i,j] + b2[i]) ----
    float t[ADIM];
#pragma unroll
    for (int i = 0; i < ADIM; ++i) {
        float acc = b2[i];
#pragma unroll
        for (int j = 0; j < HID; ++j)
            acc = fmaf(h[j], W2[i * HID + j], acc);
        // tanh(a) = 1 - 2/(exp(2a)+1); exp(2a) = 2^(2*log2(e)*a) via v_exp_f32.
        const float e = fast_exp2(acc * 2.8853900817779268f);
        t[i] = 1.0f - 2.0f / (e + 1.0f);
    }

    // ---- opt layer: z[i] = sum_j t[j]*Wopt[i,j] - bopt[i]; track bracket ----
    float z[ADIM];
    float uu[ADIM];
    float lo =  3.0e38f;   // will become min(z - u)
    float hi = -3.0e38f;   // will become max(z)
#pragma unroll
    for (int i = 0; i < ADIM; ++i) {
        float acc = -bopt[i];
#pragma unroll
        for (int j = 0; j < ADIM; ++j)
            acc = fmaf(t[j], Wopt[i * ADIM + j], acc);
        z[i] = acc;
        uu[i] = u[i];
        lo = fminf(lo, acc - uu[i]);
        hi = fmaxf(hi, acc);
    }

    // ---- bisection on dual lambda (branchless, all 32 dims unrolled) ----
#pragma unroll 1
    for (int it = 0; it < NBIS; ++it) {
        const float mid = 0.5f * (lo + hi);
        float g = -BUDGET;
#pragma unroll
        for (int i = 0; i < ADIM; ++i)
            g += fminf(fmaxf(z[i] - mid, 0.0f), uu[i]);  // v_med3_f32 pattern
        const bool pos = (g > 0.0f);
        lo = pos ? mid : lo;
        hi = pos ? hi : mid;
    }
    const float lam = 0.5f * (lo + hi);

    // ---- y = clip(z - lam, 0, u), coalesced-per-row float4 stores ----
    float4* __restrict__ op = reinterpret_cast<float4*>(out + row * ADIM);
#pragma unroll
    for (int i = 0; i < ADIM / 4; ++i) {
        float4 v;
        v.x = fminf(fmaxf(z[4*i+0] - lam, 0.0f), uu[4*i+0]);
        v.y = fminf(fmaxf(z[4*i+1] - lam, 0.0f), uu[4*i+1]);
        v.z = fminf(fmaxf(z[4*i+2] - lam, 0.0f), uu[4*i+2]);
        v.w = fminf(fmaxf(z[4*i+3] - lam, 0.0f), uu[4*i+3]);
        op[i] = v;
    }
}

extern "C" void kernel_launch(void* const* d_in, const int* in_sizes, int n_in,
                              void* d_out, int out_size, void* d_ws, size_t ws_size,
                              hipStream_t stream)
{
    const float* x    = (const float*)d_in[0];
    const float* W1   = (const float*)d_in[1];
    const float* b1   = (const float*)d_in[2];
    const float* W2   = (const float*)d_in[3];
    const float* b2   = (const float*)d_in[4];
    const float* Wopt = (const float*)d_in[5];
    const float* bopt = (const float*)d_in[6];
    const float* u    = (const float*)d_in[7];
    float* out = (float*)d_out;

    const int threads = 256;
    const int blocks  = BATCH / threads;   // 2048 blocks, exact
    anet_fused<<<blocks, threads, 0, stream>>>(x, W1, b1, W2, b2, Wopt, bopt, u, out);
}

// Round 3
// 237.569 us; speedup vs baseline: 1.3862x; 1.3862x over previous
//
#include <hip/hip_runtime.h>
#include <hip/hip_bf16.h>

// ANet fused forward, MFMA edition.
// Per wave: 16-row tile; fc1/fc2/opt via v_mfma_f32_16x16x32_bf16 (weights in
// VGPR B-fragments, loaded once); layer chaining via per-wave 2KB LDS tile
// ([16][32] f32, 16B-block XOR swizzle, same-wave only -> no barriers);
// capped-simplex bisection in 4-lane-per-row layout; coalesced float4 stores.

typedef __attribute__((ext_vector_type(8))) short bf16x8;   // 8 bf16 in 4 VGPRs
typedef __attribute__((ext_vector_type(4))) float f32x4;

constexpr int SDIM = 64, HID = 30, ADIM = 32, BATCH = 524288;
constexpr float BUDGET = 90.0f;
constexpr int NBIS = 16;           // bracket ~10.1 -> lam err ~8e-5 << 5.7e-2
constexpr int TILES = BATCH / 16;  // 32768

static __device__ __forceinline__ short f2bf(float f) {
    __hip_bfloat16 h = __float2bfloat16(f);   // RNE
    return (short)__builtin_bit_cast(unsigned short, h);
}

static __device__ __forceinline__ float fast_exp2(float a) {
#if __has_builtin(__builtin_amdgcn_exp2f)
    return __builtin_amdgcn_exp2f(a);
#else
    return exp2f(a);
#endif
}
static __device__ __forceinline__ float fast_rcp(float a) {
#if __has_builtin(__builtin_amdgcn_rcpf)
    return __builtin_amdgcn_rcpf(a);
#else
    return 1.0f / a;
#endif
}
static __device__ __forceinline__ float tanh_fast(float a) {
    // tanh(a) = 1 - 2/(exp(2a)+1); exp(2a) = 2^(2*log2(e)*a)
    const float e = fast_exp2(a * 2.8853900817779268f);
    return 1.0f - 2.0f * fast_rcp(e + 1.0f);
}

// Swizzled float-index into a wave's [16 rows][32 cols] f32 LDS tile.
// 16B blocks XOR'd with (row&7) -> conflict-free b128 row reads.
static __device__ __forceinline__ int swz(int r, int cidx) {
    return r * 32 + ((((cidx >> 2) ^ (r & 7))) << 2) + (cidx & 3);
}

__global__ __launch_bounds__(256) void anet_mfma(
    const float* __restrict__ x,
    const float* __restrict__ W1, const float* __restrict__ b1,
    const float* __restrict__ W2, const float* __restrict__ b2,
    const float* __restrict__ Wopt, const float* __restrict__ bopt,
    const float* __restrict__ u,
    float* __restrict__ out)
{
    __shared__ float smem[4 * 512];          // 2KB per wave, private
    const int lane = threadIdx.x & 63;
    const int wid  = threadIdx.x >> 6;
    float* sm = &smem[wid * 512];

    const int c = lane & 15;    // MFMA col (B/C) / row (A) index
    const int g = lane >> 4;    // k-group: lane holds k = g*8 + j

    // ---- B fragments (B[k][col] = W[col][k]), once per wave ----
    auto loadB = [&](const float* W, int stride, int ncol, int kvalid,
                     int nt, int k0) -> bf16x8 {
        const int col = c + 16 * nt;
        const bool okc = (col < ncol);
        const float* p = W + (okc ? col : 0) * stride + k0;
        bf16x8 b;
#pragma unroll
        for (int j = 0; j < 8; ++j) {
            const int kk = k0 + j;
            const int jj = (kk < kvalid) ? j : (kvalid - 1 - k0);  // stay in bounds
            float v = p[jj];
            v = (okc && kk < kvalid) ? v : 0.0f;
            b[j] = f2bf(v);
        }
        return b;
    };
    bf16x8 B1[2][2], B2[2], B3[2];
    B1[0][0] = loadB(W1, 64, HID, 64, 0, g * 8);
    B1[1][0] = loadB(W1, 64, HID, 64, 0, 32 + g * 8);
    B1[0][1] = loadB(W1, 64, HID, 64, 1, g * 8);
    B1[1][1] = loadB(W1, 64, HID, 64, 1, 32 + g * 8);
    B2[0]    = loadB(W2, HID, ADIM, HID, 0, g * 8);
    B2[1]    = loadB(W2, HID, ADIM, HID, 1, g * 8);
    B3[0]    = loadB(Wopt, ADIM, ADIM, ADIM, 0, g * 8);
    B3[1]    = loadB(Wopt, ADIM, ADIM, ADIM, 1, g * 8);

    // per-lane biases for C-layout (col = c, c+16)
    const float b1c0 = b1[c];
    const float b1c1 = (c + 16 < HID) ? b1[c + 16] : 0.0f;
    const float b2c0 = b2[c],   b2c1 = b2[c + 16];
    const float boc0 = bopt[c], boc1 = bopt[c + 16];

    // bisection layout: 4 lanes per row; lane covers dims dseg*8 .. +7
    const int rrow = lane >> 2;
    const int dseg = lane & 3;
    float u8[8];
    {
        const float4 ua = *reinterpret_cast<const float4*>(u + dseg * 8);
        const float4 ub = *reinterpret_cast<const float4*>(u + dseg * 8 + 4);
        u8[0]=ua.x; u8[1]=ua.y; u8[2]=ua.z; u8[3]=ua.w;
        u8[4]=ub.x; u8[5]=ub.y; u8[6]=ub.z; u8[7]=ub.w;
    }

    // A-fragment read from the wave's LDS tile (row = c, k = g*8 + j)
    auto read_afrag = [&]() -> bf16x8 {
        const float4 lo4 = *reinterpret_cast<const float4*>(
            &sm[c * 32 + (((2 * g) ^ (c & 7)) << 2)]);
        const float4 hi4 = *reinterpret_cast<const float4*>(
            &sm[c * 32 + (((2 * g + 1) ^ (c & 7)) << 2)]);
        bf16x8 a;
        a[0]=f2bf(lo4.x); a[1]=f2bf(lo4.y); a[2]=f2bf(lo4.z); a[3]=f2bf(lo4.w);
        a[4]=f2bf(hi4.x); a[5]=f2bf(hi4.y); a[6]=f2bf(hi4.z); a[7]=f2bf(hi4.w);
        return a;
    };

    const f32x4 zero4 = {0.0f, 0.0f, 0.0f, 0.0f};
    const int gw = blockIdx.x * 4 + wid;
    const int nw = gridDim.x * 4;

    for (int tl = gw; tl < TILES; tl += nw) {
        // ---- x A-fragments (row = tl*16 + c, k = g*8+j), fp32 -> bf16 ----
        const float* xb = x + (tl * 16 + c) * SDIM + g * 8;
        const float4 x00 = *reinterpret_cast<const float4*>(xb);
        const float4 x01 = *reinterpret_cast<const float4*>(xb + 4);
        const float4 x10 = *reinterpret_cast<const float4*>(xb + 32);
        const float4 x11 = *reinterpret_cast<const float4*>(xb + 36);
        bf16x8 xa0, xa1;
        xa0[0]=f2bf(x00.x); xa0[1]=f2bf(x00.y); xa0[2]=f2bf(x00.z); xa0[3]=f2bf(x00.w);
        xa0[4]=f2bf(x01.x); xa0[5]=f2bf(x01.y); xa0[6]=f2bf(x01.z); xa0[7]=f2bf(x01.w);
        xa1[0]=f2bf(x10.x); xa1[1]=f2bf(x10.y); xa1[2]=f2bf(x10.z); xa1[3]=f2bf(x10.w);
        xa1[4]=f2bf(x11.x); xa1[5]=f2bf(x11.y); xa1[6]=f2bf(x11.z); xa1[7]=f2bf(x11.w);

        // ---- fc1: h[16x32] = relu(x @ W1^T + b1) ----
        f32x4 acc0 = __builtin_amdgcn_mfma_f32_16x16x32_bf16(xa0, B1[0][0], zero4, 0, 0, 0);
        acc0       = __builtin_amdgcn_mfma_f32_16x16x32_bf16(xa1, B1[1][0], acc0, 0, 0, 0);
        f32x4 acc1 = __builtin_amdgcn_mfma_f32_16x16x32_bf16(xa0, B1[0][1], zero4, 0, 0, 0);
        acc1       = __builtin_amdgcn_mfma_f32_16x16x32_bf16(xa1, B1[1][1], acc1, 0, 0, 0);
#pragma unroll
        for (int q = 0; q < 4; ++q) {
            const int r = 4 * g + q;   // C-layout: row = (lane>>4)*4 + reg
            sm[swz(r, c)]      = fmaxf(acc0[q] + b1c0, 0.0f);
            sm[swz(r, c + 16)] = fmaxf(acc1[q] + b1c1, 0.0f);
        }
        asm volatile("s_waitcnt lgkmcnt(0)" ::: "memory");

        // ---- fc2: t = tanh(h @ W2^T + b2) ----
        const bf16x8 haf = read_afrag();
        acc0 = __builtin_amdgcn_mfma_f32_16x16x32_bf16(haf, B2[0], zero4, 0, 0, 0);
        acc1 = __builtin_amdgcn_mfma_f32_16x16x32_bf16(haf, B2[1], zero4, 0, 0, 0);
#pragma unroll
        for (int q = 0; q < 4; ++q) {
            const int r = 4 * g + q;
            sm[swz(r, c)]      = tanh_fast(acc0[q] + b2c0);
            sm[swz(r, c + 16)] = tanh_fast(acc1[q] + b2c1);
        }
        asm volatile("s_waitcnt lgkmcnt(0)" ::: "memory");

        // ---- opt: z = t @ Wopt^T - bopt ----
        const bf16x8 taf = read_afrag();
        acc0 = __builtin_amdgcn_mfma_f32_16x16x32_bf16(taf, B3[0], zero4, 0, 0, 0);
        acc1 = __builtin_amdgcn_mfma_f32_16x16x32_bf16(taf, B3[1], zero4, 0, 0, 0);
#pragma unroll
        for (int q = 0; q < 4; ++q) {
            const int r = 4 * g + q;
            sm[swz(r, c)]      = acc0[q] - boc0;
            sm[swz(r, c + 16)] = acc1[q] - boc1;
        }
        asm volatile("s_waitcnt lgkmcnt(0)" ::: "memory");

        // ---- bisection: 4 lanes per row, 8 dims per lane ----
        const float4 za = *reinterpret_cast<const float4*>(
            &sm[rrow * 32 + (((2 * dseg) ^ (rrow & 7)) << 2)]);
        const float4 zb = *reinterpret_cast<const float4*>(
            &sm[rrow * 32 + (((2 * dseg + 1) ^ (rrow & 7)) << 2)]);
        float z8[8] = {za.x, za.y, za.z, za.w, zb.x, zb.y, zb.z, zb.w};

        float mx = z8[0], mn = z8[0] - u8[0];
#pragma unroll
        for (int j = 1; j < 8; ++j) {
            mx = fmaxf(mx, z8[j]);
            mn = fminf(mn, z8[j] - u8[j]);
        }
        mx = fmaxf(mx, __shfl_xor(mx, 1)); mx = fmaxf(mx, __shfl_xor(mx, 2));
        mn = fminf(mn, __shfl_xor(mn, 1)); mn = fminf(mn, __shfl_xor(mn, 2));
        float lo = mn, hi = mx;

#pragma unroll 1
        for (int it = 0; it < NBIS; ++it) {
            const float mid = 0.5f * (lo + hi);
            float s0 = fminf(fmaxf(z8[0] - mid, 0.0f), u8[0])
                     + fminf(fmaxf(z8[1] - mid, 0.0f), u8[1]);
            float s1 = fminf(fmaxf(z8[2] - mid, 0.0f), u8[2])
                     + fminf(fmaxf(z8[3] - mid, 0.0f), u8[3]);
            float s2 = fminf(fmaxf(z8[4] - mid, 0.0f), u8[4])
                     + fminf(fmaxf(z8[5] - mid, 0.0f), u8[5]);
            float s3 = fminf(fmaxf(z8[6] - mid, 0.0f), u8[6])
                     + fminf(fmaxf(z8[7] - mid, 0.0f), u8[7]);
            float s = (s0 + s1) + (s2 + s3);
            s += __shfl_xor(s, 1);
            s += __shfl_xor(s, 2);
            const bool pos = (s > BUDGET);
            lo = pos ? mid : lo;
            hi = pos ? hi : mid;
        }
        const float lam = 0.5f * (lo + hi);

        // ---- y = clip(z - lam, 0, u); contiguous 1KB per wave store ----
        float4 y0, y1;
        y0.x = fminf(fmaxf(z8[0] - lam, 0.0f), u8[0]);
        y0.y = fminf(fmaxf(z8[1] - lam, 0.0f), u8[1]);
        y0.z = fminf(fmaxf(z8[2] - lam, 0.0f), u8[2]);
        y0.w = fminf(fmaxf(z8[3] - lam, 0.0f), u8[3]);
        y1.x = fminf(fmaxf(z8[4] - lam, 0.0f), u8[4]);
        y1.y = fminf(fmaxf(z8[5] - lam, 0.0f), u8[5]);
        y1.z = fminf(fmaxf(z8[6] - lam, 0.0f), u8[6]);
        y1.w = fminf(fmaxf(z8[7] - lam, 0.0f), u8[7]);
        float* ob = out + (tl * 16 + rrow) * ADIM + dseg * 8;
        *reinterpret_cast<float4*>(ob)     = y0;
        *reinterpret_cast<float4*>(ob + 4) = y1;
    }
}

extern "C" void kernel_launch(void* const* d_in, const int* in_sizes, int n_in,
                              void* d_out, int out_size, void* d_ws, size_t ws_size,
                              hipStream_t stream)
{
    const float* x    = (const float*)d_in[0];
    const float* W1   = (const float*)d_in[1];
    const float* b1   = (const float*)d_in[2];
    const float* W2   = (const float*)d_in[3];
    const float* b2   = (const float*)d_in[4];
    const float* Wopt = (const float*)d_in[5];
    const float* bopt = (const float*)d_in[6];
    const float* u    = (const float*)d_in[7];
    float* out = (float*)d_out;

    const int threads = 256;   // 4 waves/block
    const int blocks  = 1024;  // 4096 waves -> 8 tiles/wave
    anet_mfma<<<blocks, threads, 0, stream>>>(x, W1, b1, W2, b2, Wopt, bopt, u, out);
}

// Round 4
// 232.803 us; speedup vs baseline: 1.4146x; 1.0205x over previous
//
#include <hip/hip_runtime.h>
#include <hip/hip_bf16.h>

// ANet fused forward, MFMA + interior-shortcut edition.
// Per wave: 16-row tiles; fc1/fc2/opt via v_mfma_f32_16x16x32_bf16 (weights in
// VGPR B-fragments loaded once); layer chaining via per-wave 2KB LDS tile
// (16B-block XOR swizzle, same-wave only -> no barriers).
// QP projection: lambda = (sum(z)-s)/32 is the EXACT root when the solution is
// interior (0 <= z-lam <= u for all dims) -- verified per row; wave-uniform
// fallback to bisection otherwise. Cross-lane reductions via DPP quad_perm.

typedef __attribute__((ext_vector_type(8))) short bf16x8;   // 8 bf16 in 4 VGPRs
typedef __attribute__((ext_vector_type(4))) float f32x4;

constexpr int SDIM = 64, HID = 30, ADIM = 32, BATCH = 524288;
constexpr float BUDGET = 90.0f;
constexpr int NBIS = 16;           // fallback only
constexpr int TILES = BATCH / 16;  // 32768

static __device__ __forceinline__ short f2bf(float f) {
    __hip_bfloat16 h = __float2bfloat16(f);   // RNE
    return (short)__builtin_bit_cast(unsigned short, h);
}

static __device__ __forceinline__ float fast_exp2(float a) {
#if __has_builtin(__builtin_amdgcn_exp2f)
    return __builtin_amdgcn_exp2f(a);
#else
    return exp2f(a);
#endif
}
static __device__ __forceinline__ float fast_rcp(float a) {
#if __has_builtin(__builtin_amdgcn_rcpf)
    return __builtin_amdgcn_rcpf(a);
#else
    return 1.0f / a;
#endif
}
static __device__ __forceinline__ float tanh_fast(float a) {
    const float e = fast_exp2(a * 2.8853900817779268f);  // exp(2a)
    return 1.0f - 2.0f * fast_rcp(e + 1.0f);
}

// DPP quad_perm cross-lane (groups of 4 lanes): pure-VALU, no LDS.
template <int CTRL, int XOR>
static __device__ __forceinline__ float qp_mov(float v) {
#if __has_builtin(__builtin_amdgcn_mov_dpp)
    return __builtin_bit_cast(float,
        __builtin_amdgcn_mov_dpp(__builtin_bit_cast(int, v), CTRL, 0xF, 0xF, true));
#else
    return __shfl_xor(v, XOR, 4);
#endif
}
static __device__ __forceinline__ float qp_x1(float v) { return qp_mov<0xB1, 1>(v); } // [1,0,3,2]
static __device__ __forceinline__ float qp_x2(float v) { return qp_mov<0x4E, 2>(v); } // [2,3,0,1]

// Swizzled float-index into a wave's [16 rows][32 cols] f32 LDS tile.
static __device__ __forceinline__ int swz(int r, int cidx) {
    return r * 32 + ((((cidx >> 2) ^ (r & 7))) << 2) + (cidx & 3);
}

__global__ __launch_bounds__(256) void anet_mfma(
    const float* __restrict__ x,
    const float* __restrict__ W1, const float* __restrict__ b1,
    const float* __restrict__ W2, const float* __restrict__ b2,
    const float* __restrict__ Wopt, const float* __restrict__ bopt,
    const float* __restrict__ u,
    float* __restrict__ out)
{
    __shared__ float smem[4 * 512];          // 2KB per wave, private
    const int lane = threadIdx.x & 63;
    const int wid  = threadIdx.x >> 6;
    float* sm = &smem[wid * 512];

    const int c = lane & 15;    // MFMA col (B/C) / row (A) index
    const int g = lane >> 4;    // k-group: lane holds k = g*8 + j

    // ---- B fragments (B[k][col] = W[col][k]), once per wave ----
    auto loadB = [&](const float* W, int stride, int ncol, int kvalid,
                     int nt, int k0) -> bf16x8 {
        const int col = c + 16 * nt;
        const bool okc = (col < ncol);
        const float* p = W + (okc ? col : 0) * stride + k0;
        bf16x8 b;
#pragma unroll
        for (int j = 0; j < 8; ++j) {
            const int kk = k0 + j;
            const int jj = (kk < kvalid) ? j : (kvalid - 1 - k0);
            float v = p[jj];
            v = (okc && kk < kvalid) ? v : 0.0f;
            b[j] = f2bf(v);
        }
        return b;
    };
    bf16x8 B1[2][2], B2[2], B3[2];
    B1[0][0] = loadB(W1, 64, HID, 64, 0, g * 8);
    B1[1][0] = loadB(W1, 64, HID, 64, 0, 32 + g * 8);
    B1[0][1] = loadB(W1, 64, HID, 64, 1, g * 8);
    B1[1][1] = loadB(W1, 64, HID, 64, 1, 32 + g * 8);
    B2[0]    = loadB(W2, HID, ADIM, HID, 0, g * 8);
    B2[1]    = loadB(W2, HID, ADIM, HID, 1, g * 8);
    B3[0]    = loadB(Wopt, ADIM, ADIM, ADIM, 0, g * 8);
    B3[1]    = loadB(Wopt, ADIM, ADIM, ADIM, 1, g * 8);

    const float b1c0 = b1[c];
    const float b1c1 = (c + 16 < HID) ? b1[c + 16] : 0.0f;
    const float b2c0 = b2[c],   b2c1 = b2[c + 16];
    const float boc0 = bopt[c], boc1 = bopt[c + 16];

    // bisection/store layout: 4 lanes per row; lane covers dims dseg*8..+7
    const int rrow = lane >> 2;
    const int dseg = lane & 3;
    float u8[8];
    {
        const float4 ua = *reinterpret_cast<const float4*>(u + dseg * 8);
        const float4 ub = *reinterpret_cast<const float4*>(u + dseg * 8 + 4);
        u8[0]=ua.x; u8[1]=ua.y; u8[2]=ua.z; u8[3]=ua.w;
        u8[4]=ub.x; u8[5]=ub.y; u8[6]=ub.z; u8[7]=ub.w;
    }

    auto read_afrag = [&]() -> bf16x8 {
        const float4 lo4 = *reinterpret_cast<const float4*>(
            &sm[c * 32 + (((2 * g) ^ (c & 7)) << 2)]);
        const float4 hi4 = *reinterpret_cast<const float4*>(
            &sm[c * 32 + (((2 * g + 1) ^ (c & 7)) << 2)]);
        bf16x8 a;
        a[0]=f2bf(lo4.x); a[1]=f2bf(lo4.y); a[2]=f2bf(lo4.z); a[3]=f2bf(lo4.w);
        a[4]=f2bf(hi4.x); a[5]=f2bf(hi4.y); a[6]=f2bf(hi4.z); a[7]=f2bf(hi4.w);
        return a;
    };

    const f32x4 zero4 = {0.0f, 0.0f, 0.0f, 0.0f};
    const int gw = blockIdx.x * 4 + wid;   // 8192 waves
    const int nw = gridDim.x * 4;
    constexpr int TPW = 4;                 // TILES / 8192

    // prefetch x for first tile
    float4 nx0, nx1, nx2, nx3;
    {
        const float* xb = x + (gw * 16 + c) * SDIM + g * 8;
        nx0 = *reinterpret_cast<const float4*>(xb);
        nx1 = *reinterpret_cast<const float4*>(xb + 4);
        nx2 = *reinterpret_cast<const float4*>(xb + 32);
        nx3 = *reinterpret_cast<const float4*>(xb + 36);
    }

#pragma unroll
    for (int k = 0; k < TPW; ++k) {
        const int tl = gw + k * nw;
        const float4 cx0 = nx0, cx1 = nx1, cx2 = nx2, cx3 = nx3;
        if (k + 1 < TPW) {   // compile-time (loop unrolled)
            const float* xb = x + ((gw + (k + 1) * nw) * 16 + c) * SDIM + g * 8;
            nx0 = *reinterpret_cast<const float4*>(xb);
            nx1 = *reinterpret_cast<const float4*>(xb + 4);
            nx2 = *reinterpret_cast<const float4*>(xb + 32);
            nx3 = *reinterpret_cast<const float4*>(xb + 36);
        }

        bf16x8 xa0, xa1;
        xa0[0]=f2bf(cx0.x); xa0[1]=f2bf(cx0.y); xa0[2]=f2bf(cx0.z); xa0[3]=f2bf(cx0.w);
        xa0[4]=f2bf(cx1.x); xa0[5]=f2bf(cx1.y); xa0[6]=f2bf(cx1.z); xa0[7]=f2bf(cx1.w);
        xa1[0]=f2bf(cx2.x); xa1[1]=f2bf(cx2.y); xa1[2]=f2bf(cx2.z); xa1[3]=f2bf(cx2.w);
        xa1[4]=f2bf(cx3.x); xa1[5]=f2bf(cx3.y); xa1[6]=f2bf(cx3.z); xa1[7]=f2bf(cx3.w);

        // ---- fc1: h = relu(x @ W1^T + b1) ----
        f32x4 acc0 = __builtin_amdgcn_mfma_f32_16x16x32_bf16(xa0, B1[0][0], zero4, 0, 0, 0);
        acc0       = __builtin_amdgcn_mfma_f32_16x16x32_bf16(xa1, B1[1][0], acc0, 0, 0, 0);
        f32x4 acc1 = __builtin_amdgcn_mfma_f32_16x16x32_bf16(xa0, B1[0][1], zero4, 0, 0, 0);
        acc1       = __builtin_amdgcn_mfma_f32_16x16x32_bf16(xa1, B1[1][1], acc1, 0, 0, 0);
#pragma unroll
        for (int q = 0; q < 4; ++q) {
            const int r = 4 * g + q;
            sm[swz(r, c)]      = fmaxf(acc0[q] + b1c0, 0.0f);
            sm[swz(r, c + 16)] = fmaxf(acc1[q] + b1c1, 0.0f);
        }
        asm volatile("s_waitcnt lgkmcnt(0)" ::: "memory");

        // ---- fc2: t = tanh(h @ W2^T + b2) ----
        const bf16x8 haf = read_afrag();
        acc0 = __builtin_amdgcn_mfma_f32_16x16x32_bf16(haf, B2[0], zero4, 0, 0, 0);
        acc1 = __builtin_amdgcn_mfma_f32_16x16x32_bf16(haf, B2[1], zero4, 0, 0, 0);
#pragma unroll
        for (int q = 0; q < 4; ++q) {
            const int r = 4 * g + q;
            sm[swz(r, c)]      = tanh_fast(acc0[q] + b2c0);
            sm[swz(r, c + 16)] = tanh_fast(acc1[q] + b2c1);
        }
        asm volatile("s_waitcnt lgkmcnt(0)" ::: "memory");

        // ---- opt: z = t @ Wopt^T - bopt ----
        const bf16x8 taf = read_afrag();
        acc0 = __builtin_amdgcn_mfma_f32_16x16x32_bf16(taf, B3[0], zero4, 0, 0, 0);
        acc1 = __builtin_amdgcn_mfma_f32_16x16x32_bf16(taf, B3[1], zero4, 0, 0, 0);
#pragma unroll
        for (int q = 0; q < 4; ++q) {
            const int r = 4 * g + q;
            sm[swz(r, c)]      = acc0[q] - boc0;
            sm[swz(r, c + 16)] = acc1[q] - boc1;
        }
        asm volatile("s_waitcnt lgkmcnt(0)" ::: "memory");

        // ---- read z back (4 lanes per row, 8 dims each) ----
        const float4 za = *reinterpret_cast<const float4*>(
            &sm[rrow * 32 + (((2 * dseg) ^ (rrow & 7)) << 2)]);
        const float4 zb = *reinterpret_cast<const float4*>(
            &sm[rrow * 32 + (((2 * dseg + 1) ^ (rrow & 7)) << 2)]);
        const float z8[8] = {za.x, za.y, za.z, za.w, zb.x, zb.y, zb.z, zb.w};

        // ---- interior-solution shortcut ----
        // lam_unc = (sum(z) - s)/32 is the exact dual iff 0 <= z-lam <= u forall.
        float ps = ((z8[0] + z8[1]) + (z8[2] + z8[3]))
                 + ((z8[4] + z8[5]) + (z8[6] + z8[7]));
        float pmnz = fminf(fminf(fminf(z8[0], z8[1]), fminf(z8[2], z8[3])),
                           fminf(fminf(z8[4], z8[5]), fminf(z8[6], z8[7])));
        float d0 = z8[0]-u8[0], d1 = z8[1]-u8[1], d2 = z8[2]-u8[2], d3 = z8[3]-u8[3];
        float d4 = z8[4]-u8[4], d5 = z8[5]-u8[5], d6 = z8[6]-u8[6], d7 = z8[7]-u8[7];
        float pmxzu = fmaxf(fmaxf(fmaxf(d0, d1), fmaxf(d2, d3)),
                            fmaxf(fmaxf(d4, d5), fmaxf(d6, d7)));
        ps += qp_x1(ps);  ps += qp_x2(ps);
        pmnz  = fminf(pmnz,  qp_x1(pmnz));  pmnz  = fminf(pmnz,  qp_x2(pmnz));
        pmxzu = fmaxf(pmxzu, qp_x1(pmxzu)); pmxzu = fmaxf(pmxzu, qp_x2(pmxzu));
        const float lam_unc = (ps - BUDGET) * (1.0f / 32.0f);
        const bool ok = (pmxzu <= lam_unc) && (lam_unc <= pmnz);

        float lam;
        if (__all(ok)) {
            lam = lam_unc;
        } else {
            // ---- general fallback: bisection on [min(z-u), max(z)] ----
            float lo = fminf(fminf(fminf(d0, d1), fminf(d2, d3)),
                             fminf(fminf(d4, d5), fminf(d6, d7)));
            float hi = fmaxf(fmaxf(fmaxf(z8[0], z8[1]), fmaxf(z8[2], z8[3])),
                             fmaxf(fmaxf(z8[4], z8[5]), fmaxf(z8[6], z8[7])));
            lo = fminf(lo, qp_x1(lo)); lo = fminf(lo, qp_x2(lo));
            hi = fmaxf(hi, qp_x1(hi)); hi = fmaxf(hi, qp_x2(hi));
#pragma unroll 1
            for (int it = 0; it < NBIS; ++it) {
                const float mid = 0.5f * (lo + hi);
                float s = -BUDGET * 0.25f;  // each lane carries 1/4 of budget
#pragma unroll
                for (int i = 0; i < 8; ++i)
                    s += fminf(fmaxf(z8[i] - mid, 0.0f), u8[i]);
                s += qp_x1(s);
                s += qp_x2(s);
                const bool pos = (s > 0.0f);
                lo = pos ? mid : lo;
                hi = pos ? hi : mid;
            }
            const float lam_b = 0.5f * (lo + hi);
            lam = ok ? lam_unc : lam_b;
        }

        // ---- y = clip(z - lam, 0, u); contiguous 1KB per wave store ----
        float4 y0, y1;
        y0.x = fminf(fmaxf(z8[0] - lam, 0.0f), u8[0]);
        y0.y = fminf(fmaxf(z8[1] - lam, 0.0f), u8[1]);
        y0.z = fminf(fmaxf(z8[2] - lam, 0.0f), u8[2]);
        y0.w = fminf(fmaxf(z8[3] - lam, 0.0f), u8[3]);
        y1.x = fminf(fmaxf(z8[4] - lam, 0.0f), u8[4]);
        y1.y = fminf(fmaxf(z8[5] - lam, 0.0f), u8[5]);
        y1.z = fminf(fmaxf(z8[6] - lam, 0.0f), u8[6]);
        y1.w = fminf(fmaxf(z8[7] - lam, 0.0f), u8[7]);
        float* ob = out + (tl * 16 + rrow) * ADIM + dseg * 8;
        *reinterpret_cast<float4*>(ob)     = y0;
        *reinterpret_cast<float4*>(ob + 4) = y1;
    }
}

extern "C" void kernel_launch(void* const* d_in, const int* in_sizes, int n_in,
                              void* d_out, int out_size, void* d_ws, size_t ws_size,
                              hipStream_t stream)
{
    const float* x    = (const float*)d_in[0];
    const float* W1   = (const float*)d_in[1];
    const float* b1   = (const float*)d_in[2];
    const float* W2   = (const float*)d_in[3];
    const float* b2   = (const float*)d_in[4];
    const float* Wopt = (const float*)d_in[5];
    const float* bopt = (const float*)d_in[6];
    const float* u    = (const float*)d_in[7];
    float* out = (float*)d_out;

    const int threads = 256;   // 4 waves/block
    const int blocks  = 2048;  // 8192 waves -> 4 tiles/wave
    anet_mfma<<<blocks, threads, 0, stream>>>(x, W1, b1, W2, b2, Wopt, bopt, u, out);
}